// Round 5
// baseline (435.825 us; speedup 1.0000x reference)
//
#include <hip/hip_runtime.h>
#include <hip/hip_bf16.h>

// ---------------- problem constants ----------------
#define DIMD 384
#define HEADS 6
#define DH 64
#define LEVELS 3
#define POINTS 4
#define FFN 1024
#define BB 4
#define NQ 4096
#define NV 21504
#define MQ (BB*NQ)   // 16384
#define MV (BB*NV)   // 86016
#define EPSF 1e-6f

typedef __hip_bfloat16 bf16;
typedef __attribute__((ext_vector_type(8))) short bf16x8;
typedef __attribute__((ext_vector_type(4))) float f32x4;

__device__ __forceinline__ float wave_sum(float v){
  #pragma unroll
  for(int o=32;o;o>>=1) v += __shfl_xor(v,o);
  return v;
}

// ---------------- weight prep: fp32 -> bf16; Wv gets fn_g folded in ----------------
__global__ __launch_bounds__(256) void prep_k(
  const float* __restrict__ Wv, const float* __restrict__ Wo,
  const float* __restrict__ W1, const float* __restrict__ W2,
  const float* __restrict__ Woff, const float* __restrict__ Waw,
  const float* __restrict__ boff, const float* __restrict__ baw,
  const float* __restrict__ fng,
  bf16* __restrict__ wvg, bf16* __restrict__ wo, bf16* __restrict__ w1,
  bf16* __restrict__ w2, bf16* __restrict__ wcat, float* __restrict__ bcat)
{
  int i = blockIdx.x*256 + threadIdx.x;
  if(i < 147456){ wvg[i] = __float2bfloat16(Wv[i] * fng[i % 384]); return; }
  i -= 147456;
  if(i < 147456){ wo[i] = __float2bfloat16(Wo[i]); return; }
  i -= 147456;
  if(i < 393216){ w1[i] = __float2bfloat16(W1[i]); return; }
  i -= 393216;
  if(i < 393216){ w2[i] = __float2bfloat16(W2[i]); return; }
  i -= 393216;
  if(i < 98304){
    int r = i/384, c = i - r*384;
    float v = r<144 ? Woff[r*384+c] : (r<216 ? Waw[(r-144)*384+c] : 0.f);
    wcat[i] = __float2bfloat16(v); return;
  }
  i -= 98304;
  if(i < 256){ bcat[i] = i<144 ? boff[i] : (i<216 ? baw[i-144] : 0.f); }
}

// ---------------- v-proj constant prep: u1[n] = <Wv[n,:],g>, c0[n] = <Wv[n,:],b> + bv[n] ----------------
__global__ __launch_bounds__(256) void vprep_k(
    const float* __restrict__ Wv, const float* __restrict__ fng,
    const float* __restrict__ fnb, const float* __restrict__ bv,
    float* __restrict__ u1, float* __restrict__ c0)
{
  const int n = blockIdx.x*4 + (threadIdx.x>>6);
  const int lane = threadIdx.x & 63;
  float s1=0.f, s0=0.f;
  #pragma unroll
  for(int i=0;i<6;i++){
    const int k = lane + i*64;
    const float w = Wv[(size_t)n*DIMD + k];
    s1 += w*fng[k]; s0 += w*fnb[k];
  }
  s1 = wave_sum(s1); s0 = wave_sum(s0);
  if(lane==0){ u1[n] = s1; c0[n] = s0 + bv[n]; }
}

// ---------------- row LayerNorm (DIMD=384), templated in/out dtype ----------------
template<int INBF,int OUTBF,int FINAL>
__global__ __launch_bounds__(256) void ln_k(const void* __restrict__ xv,
    const float* __restrict__ g, const float* __restrict__ b,
    const float* __restrict__ q, const float* __restrict__ gamma,
    void* __restrict__ outv, int nrows)
{
  int row = blockIdx.x*4 + (threadIdx.x>>6);
  int lane = threadIdx.x & 63;
  if(row >= nrows) return;
  float vals[6];
  float s=0.f, s2=0.f;
  #pragma unroll
  for(int i=0;i<6;i++){
    float v;
    if constexpr(INBF) v = __bfloat162float(((const bf16*)xv)[(size_t)row*DIMD + lane + i*64]);
    else               v = ((const float*)xv)[(size_t)row*DIMD + lane + i*64];
    vals[i]=v; s += v; s2 += v*v;
  }
  s = wave_sum(s); s2 = wave_sum(s2);
  float m = s*(1.f/DIMD);
  float var = s2*(1.f/DIMD) - m*m;
  float r = rsqrtf(var + EPSF);
  #pragma unroll
  for(int i=0;i<6;i++){
    int k = lane + i*64;
    float t = (vals[i]-m)*r*g[k] + b[k];
    if constexpr(FINAL){
      t = q[(size_t)row*DIMD + k] + gamma[k]*t;
      ((float*)outv)[(size_t)row*DIMD + k] = t;
    } else if constexpr(OUTBF){
      ((bf16*)outv)[(size_t)row*DIMD + k] = __float2bfloat16(t);
    } else {
      ((float*)outv)[(size_t)row*DIMD + k] = t;
    }
  }
}

// ---------------- fused LN + value projection, v2 ----------------
// out[128][384] = rs*(feat_bf16 @ Wvg^T) - rs*m*u1 + c0, single N pass, BK=64.
// 512 thr = 8 waves (2M x 4N). Row stats accumulated during A staging.
// LDS: As[128][64] + Bs[384][64] bf16, XOR-swizzled (T2), + stats[128][2].
__global__ __launch_bounds__(512,4) void vproj2_k(
    const float* __restrict__ feat, const bf16* __restrict__ wvg,
    const float* __restrict__ u1, const float* __restrict__ c0,
    bf16* __restrict__ out)
{
  extern __shared__ char smem[];
  short* As = (short*)smem;                       // [128][64] swizzled
  short* Bs = (short*)(smem + 128*64*2);          // [384][64] swizzled
  float* st = (float*)(smem + (128+384)*64*2);    // [128][2] = {rs, m*rs}
  const int tid = threadIdx.x;
  const int wid = tid>>6, lane = tid&63;
  const int m0 = blockIdx.x*128;
  const int ar_ = tid>>2;            // staging row 0..127
  const int ac_ = (tid&3)*16;        // staging col (shorts)
  const int wr = wid>>2, wc = wid&3; // wave grid 2M x 4N
  float s=0.f, s2=0.f;
  f32x4 acc[4][6] = {};

  for(int k0=0;k0<DIMD;k0+=64){
    // ---- stage A: 16 fp32 -> bf16, accumulate row stats ----
    {
      const float* fr = feat + (size_t)(m0+ar_)*DIMD + k0 + ac_;
      float fv[16];
      *(float4*)(fv+0)  = ((const float4*)fr)[0];
      *(float4*)(fv+4)  = ((const float4*)fr)[1];
      *(float4*)(fv+8)  = ((const float4*)fr)[2];
      *(float4*)(fv+12) = ((const float4*)fr)[3];
      bf16x8 p0, p1;
      #pragma unroll
      for(int e=0;e<8;e++){
        p0[e] = __builtin_bit_cast(short, __float2bfloat16(fv[e]));
        p1[e] = __builtin_bit_cast(short, __float2bfloat16(fv[8+e]));
        s  += fv[e] + fv[8+e];
        s2 += fv[e]*fv[e] + fv[8+e]*fv[8+e];
      }
      const int sw = (ar_&7)<<3;
      *(bf16x8*)(As + ar_*64 + ((ac_    ) ^ sw)) = p0;
      *(bf16x8*)(As + ar_*64 + ((ac_ + 8) ^ sw)) = p1;
    }
    // ---- stage B: Wvg chunk [384][64] ----
    #pragma unroll
    for(int u=0;u<6;u++){
      const int t = u*512 + tid;        // 0..3071
      const int n = t>>3, cp = (t&7)*8;
      bf16x8 w8 = *(const bf16x8*)(wvg + (size_t)n*DIMD + k0 + cp);
      *(bf16x8*)(Bs + n*64 + (cp ^ ((n&7)<<3))) = w8;
    }
    __syncthreads();
    #pragma unroll
    for(int ks=0;ks<2;ks++){
      bf16x8 af[4], bfr[6];
      #pragma unroll
      for(int i=0;i<4;i++){
        const int ar = wr*64 + i*16 + (lane&15);
        af[i] = *(const bf16x8*)(As + ar*64 + ((ks*32 + (lane>>4)*8) ^ ((ar&7)<<3)));
      }
      #pragma unroll
      for(int j=0;j<6;j++){
        const int br = wc*96 + j*16 + (lane&15);
        bfr[j] = *(const bf16x8*)(Bs + br*64 + ((ks*32 + (lane>>4)*8) ^ ((br&7)<<3)));
      }
      #pragma unroll
      for(int i=0;i<4;i++)
        #pragma unroll
        for(int j=0;j<6;j++)
          acc[i][j] = __builtin_amdgcn_mfma_f32_16x16x32_bf16(af[i], bfr[j], acc[i][j], 0,0,0);
    }
    __syncthreads();
  }
  // ---- finalize row stats (reduce over the 4 staging threads per row) ----
  s  += __shfl_xor(s,1);  s  += __shfl_xor(s,2);
  s2 += __shfl_xor(s2,1); s2 += __shfl_xor(s2,2);
  if((tid&3)==0){
    const float m  = s*(1.f/DIMD);
    const float rs = rsqrtf(s2*(1.f/DIMD) - m*m + EPSF);
    st[2*ar_] = rs; st[2*ar_+1] = m*rs;
  }
  __syncthreads();
  // ---- epilogue ----
  #pragma unroll
  for(int i=0;i<4;i++){
    const int r0 = wr*64 + i*16 + (lane>>4)*4;
    #pragma unroll
    for(int j=0;j<6;j++){
      const int col = wc*96 + j*16 + (lane&15);
      const float u1c = u1[col], c0c = c0[col];
      #pragma unroll
      for(int rr=0;rr<4;rr++){
        const int r = r0 + rr;
        const float v = st[2*r]*acc[i][j][rr] - st[2*r+1]*u1c + c0c;
        out[(size_t)(m0+r)*DIMD + col] = __float2bfloat16(v);
      }
    }
  }
}

// ---------------- bf16 MFMA GEMM: C = epi(A @ W^T + bias [+ res]) ----------------
template<int GELU_,int STBF,int RES>
__global__ __launch_bounds__(256) void mgemm_k(
    const bf16* __restrict__ A, const bf16* __restrict__ Bw,
    const float* __restrict__ bias, const bf16* __restrict__ res,
    void* __restrict__ Cv, int M, int K, int Nreal, int ldc)
{
  __shared__ __align__(16) short As[128*64];
  __shared__ __align__(16) short Bs[128*64];
  const int tid  = threadIdx.x;
  const int wid  = tid>>6, lane = tid&63;
  const int wr   = wid>>1, wc = wid&1;
  const int m0   = blockIdx.y*128, n0 = blockIdx.x*128;
  f32x4 acc[4][4] = {};

  const int sr = (lane>>3);
  const int sc = (lane&7)*8;

  for(int k0=0; k0<K; k0+=64){
    #pragma unroll
    for(int u=0;u<4;u++){
      const int t = wid*4 + u;
      const int r = t*8 + sr;
      const bf16* srcA = A  + (size_t)(m0+r)*K + k0 + sc;
      const bf16* srcB = Bw + (size_t)(n0+r)*K + k0 + sc;
      __builtin_amdgcn_global_load_lds((const __attribute__((address_space(1))) void*)srcA,
          (__attribute__((address_space(3))) void*)(As + t*512), 16, 0, 0);
      __builtin_amdgcn_global_load_lds((const __attribute__((address_space(1))) void*)srcB,
          (__attribute__((address_space(3))) void*)(Bs + t*512), 16, 0, 0);
    }
    asm volatile("s_waitcnt vmcnt(0)" ::: "memory");
    __syncthreads();
    #pragma unroll
    for(int ks=0;ks<2;ks++){
      bf16x8 af[4], bfr[4];
      #pragma unroll
      for(int i=0;i<4;i++){
        const int ar = wr*64 + i*16 + (lane&15);
        af[i]  = *(const bf16x8*)(As + ar*64 + ks*32 + (lane>>4)*8);
        const int br = wc*64 + i*16 + (lane&15);
        bfr[i] = *(const bf16x8*)(Bs + br*64 + ks*32 + (lane>>4)*8);
      }
      #pragma unroll
      for(int i=0;i<4;i++)
        #pragma unroll
        for(int j=0;j<4;j++)
          acc[i][j] = __builtin_amdgcn_mfma_f32_16x16x32_bf16(af[i], bfr[j], acc[i][j], 0,0,0);
    }
    __syncthreads();
  }
  #pragma unroll
  for(int i=0;i<4;i++){
    const int rbase = m0 + wr*64 + i*16 + (lane>>4)*4;
    #pragma unroll
    for(int j=0;j<4;j++){
      const int col = n0 + wc*64 + j*16 + (lane&15);
      if(col >= Nreal) continue;
      const float bv = bias[col];
      #pragma unroll
      for(int rr=0;rr<4;rr++){
        const int rowg = rbase + rr;
        float v = acc[i][j][rr] + bv;
        if constexpr(RES) v += __bfloat162float(res[(size_t)rowg*ldc + col]);
        if constexpr(GELU_){ float u=v; v = 0.5f*u*(1.f+tanhf(0.7978845608028654f*(u+0.044715f*u*u*u))); }
        if constexpr(STBF) ((bf16*)Cv)[(size_t)rowg*ldc + col] = __float2bfloat16(v);
        else               ((float*)Cv)[(size_t)rowg*ldc + col] = v;
      }
    }
  }
}

// ---------------- MSDA point prep: one THREAD per (bq, head) ----------------
__global__ __launch_bounds__(256) void msda_prep_k(
    const float* __restrict__ offaw, const float* __restrict__ refp,
    const int* __restrict__ sshapes, const int* __restrict__ lstart,
    uint2* __restrict__ pairs)
{
  const int t = blockIdx.x*256 + threadIdx.x;
  if(t >= MQ*HEADS) return;
  const int bq = t/6, h = t - bq*6;
  const int b  = bq >> 12;
  const float* row = offaw + (size_t)bq*216;
  float awv[12];
  float mx = -1e30f;
  #pragma unroll
  for(int i=0;i<12;i++){ awv[i] = row[144 + h*12 + i]; mx = fmaxf(mx, awv[i]); }
  float ssum = 0.f;
  #pragma unroll
  for(int i=0;i<12;i++){ awv[i] = __expf(awv[i]-mx); ssum += awv[i]; }
  const float inv = 1.f/ssum;
  uint2* pw = pairs + (size_t)t*48;
  int c48 = 0;
  #pragma unroll
  for(int l=0;l<LEVELS;l++){
    const int hh = sshapes[2*l], ww = sshapes[2*l+1];
    const int st = lstart[l];
    const float rx = refp[((size_t)bq*LEVELS + l)*2 + 0];
    const float ry = refp[((size_t)bq*LEVELS + l)*2 + 1];
    #pragma unroll
    for(int p=0;p<POINTS;p++){
      const float ox = row[((h*LEVELS + l)*POINTS + p)*2 + 0];
      const float oy = row[((h*LEVELS + l)*POINTS + p)*2 + 1];
      const float px = (rx + ox/(float)ww)*(float)ww - 0.5f;
      const float py = (ry + oy/(float)hh)*(float)hh - 0.5f;
      const float fx0 = floorf(px), fy0 = floorf(py);
      const int x0 = (int)fx0, y0 = (int)fy0;
      const float wx1 = px - fx0, wx0 = 1.f - wx1;
      const float wy1 = py - fy0, wy0 = 1.f - wy1;
      const float aww = awv[l*POINTS+p]*inv;
      #pragma unroll
      for(int c=0;c<4;c++){
        const int xi = x0 + (c&1);
        const int yi = y0 + (c>>1);
        const float wgt = (c&1 ? wx1 : wx0) * (c>>1 ? wy1 : wy0);
        const bool valid = (xi>=0) & (xi<=ww-1) & (yi>=0) & (yi<=hh-1);
        const int cx = min(max(xi,0), ww-1);
        const int cy = min(max(yi,0), hh-1);
        const unsigned off = (unsigned)((((b*NV + st + cy*ww + cx)*DIMD) + h*DH)*2);
        const float w = valid ? wgt*aww : 0.f;
        uint2 pr; pr.x = off; pr.y = __float_as_uint(w);
        pw[c48++] = pr;
      }
    }
  }
}

// ---------------- MSDA gather: half-wave (32 lanes) per (bq,h), 2 ch/lane ----------------
__global__ __launch_bounds__(256) void msda_gather_k(
    const bf16* __restrict__ v, const uint2* __restrict__ pairs,
    bf16* __restrict__ out)
{
  const int wid  = blockIdx.x*4 + (threadIdx.x>>6);
  const int lane = threadIdx.x & 63;
  const int pid  = wid*2 + (lane>>5);
  const int ch   = lane & 31;
  const uint2* pw = pairs + (size_t)pid*48;
  const char* vb = (const char*)v;
  float a0 = 0.f, a1 = 0.f;
  #pragma unroll
  for(int c=0;c<48;c++){
    const uint2 pr = pw[c];
    const unsigned g = *(const unsigned*)(vb + pr.x + (ch<<2));
    const float w = __uint_as_float(pr.y);
    const float lo = __uint_as_float(g << 16);
    const float hi = __uint_as_float(g & 0xffff0000u);
    a0 = fmaf(w, lo, a0);
    a1 = fmaf(w, hi, a1);
  }
  const int bq = pid/6, h = pid - bq*6;
  const unsigned u0 = (unsigned)__builtin_bit_cast(unsigned short, __float2bfloat16(a0));
  const unsigned u1 = (unsigned)__builtin_bit_cast(unsigned short, __float2bfloat16(a1));
  *(unsigned*)((char*)out + (size_t)bq*768 + h*128 + (ch<<2)) = u0 | (u1<<16);
}

// ---------------- launcher ----------------
static inline size_t rnd(size_t x){ return (x + 511) & ~(size_t)511; }

extern "C" void kernel_launch(void* const* d_in, const int* in_sizes, int n_in,
                              void* d_out, int out_size, void* d_ws, size_t ws_size,
                              hipStream_t stream)
{
  const float* query = (const float*)d_in[0];
  const float* refp  = (const float*)d_in[1];
  const float* feat  = (const float*)d_in[2];
  const int*   sshp  = (const int*)d_in[3];
  const int*   lst   = (const int*)d_in[4];
  const float* qn_g  = (const float*)d_in[5];
  const float* qn_b  = (const float*)d_in[6];
  const float* fn_g  = (const float*)d_in[7];
  const float* fn_b  = (const float*)d_in[8];
  const float* W_off = (const float*)d_in[9];
  const float* b_off = (const float*)d_in[10];
  const float* W_aw  = (const float*)d_in[11];
  const float* b_aw  = (const float*)d_in[12];
  const float* W_v   = (const float*)d_in[13];
  const float* b_v   = (const float*)d_in[14];
  const float* W_o   = (const float*)d_in[15];
  const float* b_o   = (const float*)d_in[16];
  const float* n1_g  = (const float*)d_in[17];
  const float* n1_b  = (const float*)d_in[18];
  const float* W1    = (const float*)d_in[19];
  const float* b1    = (const float*)d_in[20];
  const float* W2    = (const float*)d_in[21];
  const float* b2    = (const float*)d_in[22];
  const float* n2_g  = (const float*)d_in[23];
  const float* n2_b  = (const float*)d_in[24];
  const float* gam   = (const float*)d_in[25];

  // ---- workspace layout (~160 MB) ----
  char* p = (char*)d_ws;
  bf16* vbuf  = (bf16*)p;  p += rnd((size_t)MV*DIMD*2);
  bf16* qn    = (bf16*)p;  p += rnd((size_t)MQ*DIMD*2);
  bf16* wvg   = (bf16*)p;  p += rnd((size_t)147456*2);
  bf16* wo    = (bf16*)p;  p += rnd((size_t)147456*2);
  bf16* w1    = (bf16*)p;  p += rnd((size_t)393216*2);
  bf16* w2    = (bf16*)p;  p += rnd((size_t)393216*2);
  bf16* wcat  = (bf16*)p;  p += rnd((size_t)98304*2);
  float* bcat = (float*)p; p += rnd((size_t)256*4);
  float* u1   = (float*)p; p += rnd((size_t)384*4);
  float* c0   = (float*)p; p += rnd((size_t)384*4);
  bf16* hbuf  = (bf16*)p;  p += rnd((size_t)MQ*FFN*2);
  bf16* ybuf  = (bf16*)p;  p += rnd((size_t)MQ*DIMD*2);
  float* offaw = (float*)p; p += rnd((size_t)MQ*216*4);
  bf16*  msda  = (bf16*)p;  p += rnd((size_t)MQ*DIMD*2);
  bf16*  x1    = (bf16*)p;  p += rnd((size_t)MQ*DIMD*2);
  bf16*  x2    = (bf16*)p;  p += rnd((size_t)MQ*DIMD*2);
  // pairs table (37.7 MB) aliases hbuf+ybuf (both dead until FFN steps)
  uint2* pairs = (uint2*)hbuf;

  // dynamic-LDS cap for vproj2_k: 65 KB tiles + 1 KB stats
  const int VPROJ_LDS = (128+384)*64*2 + 128*2*4;   // 66,560 B -> 2 blocks/CU
  hipFuncSetAttribute((const void*)vproj2_k,
                      hipFuncAttributeMaxDynamicSharedMemorySize, VPROJ_LDS);

  // 1. weights -> bf16 (+g-fold, concat/pad) ; v-proj LN constants
  prep_k<<<4609, 256, 0, stream>>>(W_v, W_o, W1, W2, W_off, W_aw, b_off, b_aw,
                                   fn_g, wvg, wo, w1, w2, wcat, bcat);
  vprep_k<<<DIMD/4, 256, 0, stream>>>(W_v, fn_g, fn_b, b_v, u1, c0);
  // 2. qn = LN(query) bf16
  ln_k<0,1,0><<<MQ/4, 256, 0, stream>>>(query, qn_g, qn_b, nullptr, nullptr, qn, MQ);
  // 3. v = LN(feat) @ W_v^T + b_v  (fused v2: stats-in-staging, single N pass)
  vproj2_k<<<MV/128, 512, VPROJ_LDS, stream>>>(feat, wvg, u1, c0, vbuf);
  // 4. offsets|logits = qn @ Wcat^T + bcat  (fp32, ldc 216, Npad 256)
  mgemm_k<0,0,0><<<dim3(2, MQ/128), 256, 0, stream>>>(qn, wcat, bcat, nullptr, offaw,
                                                      MQ, DIMD, 216, 216);
  // 4.5 point prep
  msda_prep_k<<<(MQ*HEADS + 255)/256, 256, 0, stream>>>(offaw, refp, sshp, lst, pairs);
  // 5. gather -> msda bf16
  msda_gather_k<<<MQ*HEADS/8, 256, 0, stream>>>(vbuf, pairs, msda);
  // 6. x1 = qn + msda @ W_o^T + b_o  (bf16)
  mgemm_k<0,1,1><<<dim3(3, MQ/128), 256, 0, stream>>>(msda, wo, b_o, qn, x1,
                                                      MQ, DIMD, DIMD, DIMD);
  // 7. x2 = LN(x1) bf16
  ln_k<1,1,0><<<MQ/4, 256, 0, stream>>>(x1, n1_g, n1_b, nullptr, nullptr, x2, MQ);
  // 8. h = gelu(x2 @ W1^T + b1)  (bf16)
  mgemm_k<1,1,0><<<dim3(8, MQ/128), 256, 0, stream>>>(x2, w1, b1, nullptr, hbuf,
                                                      MQ, DIMD, FFN, FFN);
  // 9. y = x2 + h @ W2^T + b2  (bf16)
  mgemm_k<0,1,1><<<dim3(3, MQ/128), 256, 0, stream>>>(hbuf, w2, b2, x2, ybuf,
                                                      MQ, FFN, DIMD, DIMD);
  // 10. out = query + gamma * LN(y)
  ln_k<1,0,1><<<MQ/4, 256, 0, stream>>>(ybuf, n2_g, n2_b, query, gam, (float*)d_out, MQ);
}

// Round 6
// 309.598 us; speedup vs baseline: 1.4077x; 1.4077x over previous
//
#include <hip/hip_runtime.h>
#include <hip/hip_bf16.h>

// ---------------- problem constants ----------------
#define DIMD 384
#define HEADS 6
#define DH 64
#define LEVELS 3
#define POINTS 4
#define FFN 1024
#define BB 4
#define NQ 4096
#define NV 21504
#define MQ (BB*NQ)   // 16384
#define MV (BB*NV)   // 86016
#define EPSF 1e-6f

typedef __hip_bfloat16 bf16;
typedef __attribute__((ext_vector_type(8))) short bf16x8;
typedef __attribute__((ext_vector_type(4))) float f32x4;

__device__ __forceinline__ float wave_sum(float v){
  #pragma unroll
  for(int o=32;o;o>>=1) v += __shfl_xor(v,o);
  return v;
}

// ---------------- weight prep: fp32 -> bf16; Wv gets fn_g folded in ----------------
__global__ __launch_bounds__(256) void prep_k(
  const float* __restrict__ Wv, const float* __restrict__ Wo,
  const float* __restrict__ W1, const float* __restrict__ W2,
  const float* __restrict__ Woff, const float* __restrict__ Waw,
  const float* __restrict__ boff, const float* __restrict__ baw,
  const float* __restrict__ fng,
  bf16* __restrict__ wvg, bf16* __restrict__ wo, bf16* __restrict__ w1,
  bf16* __restrict__ w2, bf16* __restrict__ wcat, float* __restrict__ bcat)
{
  int i = blockIdx.x*256 + threadIdx.x;
  if(i < 147456){ wvg[i] = __float2bfloat16(Wv[i] * fng[i % 384]); return; }
  i -= 147456;
  if(i < 147456){ wo[i] = __float2bfloat16(Wo[i]); return; }
  i -= 147456;
  if(i < 393216){ w1[i] = __float2bfloat16(W1[i]); return; }
  i -= 393216;
  if(i < 393216){ w2[i] = __float2bfloat16(W2[i]); return; }
  i -= 393216;
  if(i < 98304){
    int r = i/384, c = i - r*384;
    float v = r<144 ? Woff[r*384+c] : (r<216 ? Waw[(r-144)*384+c] : 0.f);
    wcat[i] = __float2bfloat16(v); return;
  }
  i -= 98304;
  if(i < 256){ bcat[i] = i<144 ? boff[i] : (i<216 ? baw[i-144] : 0.f); }
}

// ---------------- v-proj constant prep: u1[n] = <Wv[n,:],g>, c0[n] = <Wv[n,:],b> + bv[n] ----------------
__global__ __launch_bounds__(256) void vprep_k(
    const float* __restrict__ Wv, const float* __restrict__ fng,
    const float* __restrict__ fnb, const float* __restrict__ bv,
    float* __restrict__ u1, float* __restrict__ c0)
{
  const int n = blockIdx.x*4 + (threadIdx.x>>6);
  const int lane = threadIdx.x & 63;
  float s1=0.f, s0=0.f;
  #pragma unroll
  for(int i=0;i<6;i++){
    const int k = lane + i*64;
    const float w = Wv[(size_t)n*DIMD + k];
    s1 += w*fng[k]; s0 += w*fnb[k];
  }
  s1 = wave_sum(s1); s0 = wave_sum(s0);
  if(lane==0){ u1[n] = s1; c0[n] = s0 + bv[n]; }
}

// ---------------- row LayerNorm (DIMD=384), templated in/out dtype ----------------
template<int INBF,int OUTBF,int FINAL>
__global__ __launch_bounds__(256) void ln_k(const void* __restrict__ xv,
    const float* __restrict__ g, const float* __restrict__ b,
    const float* __restrict__ q, const float* __restrict__ gamma,
    void* __restrict__ outv, int nrows)
{
  int row = blockIdx.x*4 + (threadIdx.x>>6);
  int lane = threadIdx.x & 63;
  if(row >= nrows) return;
  float vals[6];
  float s=0.f, s2=0.f;
  #pragma unroll
  for(int i=0;i<6;i++){
    float v;
    if constexpr(INBF) v = __bfloat162float(((const bf16*)xv)[(size_t)row*DIMD + lane + i*64]);
    else               v = ((const float*)xv)[(size_t)row*DIMD + lane + i*64];
    vals[i]=v; s += v; s2 += v*v;
  }
  s = wave_sum(s); s2 = wave_sum(s2);
  float m = s*(1.f/DIMD);
  float var = s2*(1.f/DIMD) - m*m;
  float r = rsqrtf(var + EPSF);
  #pragma unroll
  for(int i=0;i<6;i++){
    int k = lane + i*64;
    float t = (vals[i]-m)*r*g[k] + b[k];
    if constexpr(FINAL){
      t = q[(size_t)row*DIMD + k] + gamma[k]*t;
      ((float*)outv)[(size_t)row*DIMD + k] = t;
    } else if constexpr(OUTBF){
      ((bf16*)outv)[(size_t)row*DIMD + k] = __float2bfloat16(t);
    } else {
      ((float*)outv)[(size_t)row*DIMD + k] = t;
    }
  }
}

// ---------------- fused LN + value projection, v3 (spill-free) ----------------
// 64-row block, 512 thr = 8 waves, wave grid 1M x 8N: per-wave 64x48, acc[4][3].
// out = rs*(feat_bf16 @ Wvg^T) - rs*m*u1 + c0. Stats accumulated during staging.
// LDS 56.5 KB static -> 2 blocks/CU at <=128 VGPR.
__global__ __launch_bounds__(512,4) void vproj3_k(
    const float* __restrict__ feat, const bf16* __restrict__ wvg,
    const float* __restrict__ u1, const float* __restrict__ c0,
    bf16* __restrict__ out)
{
  __shared__ __align__(16) short As[64*64];     // swizzled
  __shared__ __align__(16) short Bs[384*64];    // swizzled
  __shared__ float st[64*2];                    // {rs, m*rs}
  const int tid = threadIdx.x;
  const int wid = tid>>6, lane = tid&63;
  const int m0 = blockIdx.x*64;
  const int ar_ = tid>>3;            // staging row 0..63
  const int ac_ = (tid&7)*8;         // staging col (fp32/short elems)
  float s=0.f, s2=0.f;
  f32x4 acc[4][3] = {};

  for(int k0=0;k0<DIMD;k0+=64){
    // ---- stage A: 8 fp32 -> bf16x8, accumulate row stats ----
    {
      const float* fr = feat + (size_t)(m0+ar_)*DIMD + k0 + ac_;
      float4 va = ((const float4*)fr)[0];
      float4 vb = ((const float4*)fr)[1];
      bf16x8 p;
      p[0]=__builtin_bit_cast(short,__float2bfloat16(va.x));
      p[1]=__builtin_bit_cast(short,__float2bfloat16(va.y));
      p[2]=__builtin_bit_cast(short,__float2bfloat16(va.z));
      p[3]=__builtin_bit_cast(short,__float2bfloat16(va.w));
      p[4]=__builtin_bit_cast(short,__float2bfloat16(vb.x));
      p[5]=__builtin_bit_cast(short,__float2bfloat16(vb.y));
      p[6]=__builtin_bit_cast(short,__float2bfloat16(vb.z));
      p[7]=__builtin_bit_cast(short,__float2bfloat16(vb.w));
      s  += va.x+va.y+va.z+va.w + vb.x+vb.y+vb.z+vb.w;
      s2 += va.x*va.x+va.y*va.y+va.z*va.z+va.w*va.w
          + vb.x*vb.x+vb.y*vb.y+vb.z*vb.z+vb.w*vb.w;
      *(bf16x8*)(As + ar_*64 + (ac_ ^ ((ar_&7)<<3))) = p;
    }
    // ---- stage B: Wvg chunk [384][64] ----
    #pragma unroll
    for(int u=0;u<6;u++){
      const int t = u*512 + tid;        // 0..3071
      const int n = t>>3, cp = (t&7)*8;
      bf16x8 w8 = *(const bf16x8*)(wvg + (size_t)n*DIMD + k0 + cp);
      *(bf16x8*)(Bs + n*64 + (cp ^ ((n&7)<<3))) = w8;
    }
    __syncthreads();
    #pragma unroll
    for(int ks=0;ks<2;ks++){
      const int cbase = ks*32 + (lane>>4)*8;
      bf16x8 af[4], bfr[3];
      #pragma unroll
      for(int i=0;i<4;i++){
        const int ar = i*16 + (lane&15);
        af[i] = *(const bf16x8*)(As + ar*64 + (cbase ^ ((ar&7)<<3)));
      }
      #pragma unroll
      for(int j=0;j<3;j++){
        const int br = wid*48 + j*16 + (lane&15);
        bfr[j] = *(const bf16x8*)(Bs + br*64 + (cbase ^ ((br&7)<<3)));
      }
      #pragma unroll
      for(int i=0;i<4;i++)
        #pragma unroll
        for(int j=0;j<3;j++)
          acc[i][j] = __builtin_amdgcn_mfma_f32_16x16x32_bf16(af[i], bfr[j], acc[i][j], 0,0,0);
    }
    __syncthreads();
  }
  // ---- finalize row stats (reduce over the 8 staging threads per row) ----
  s  += __shfl_xor(s,1);  s  += __shfl_xor(s,2);  s  += __shfl_xor(s,4);
  s2 += __shfl_xor(s2,1); s2 += __shfl_xor(s2,2); s2 += __shfl_xor(s2,4);
  if((tid&7)==0){
    const float m  = s*(1.f/DIMD);
    const float rs = rsqrtf(s2*(1.f/DIMD) - m*m + EPSF);
    st[2*ar_] = rs; st[2*ar_+1] = m*rs;
  }
  __syncthreads();
  // ---- epilogue ----
  #pragma unroll
  for(int i=0;i<4;i++){
    const int r0 = i*16 + (lane>>4)*4;
    #pragma unroll
    for(int j=0;j<3;j++){
      const int col = wid*48 + j*16 + (lane&15);
      const float u1c = u1[col], c0c = c0[col];
      #pragma unroll
      for(int rr=0;rr<4;rr++){
        const int r = r0 + rr;
        const float v = st[2*r]*acc[i][j][rr] - st[2*r+1]*u1c + c0c;
        out[(size_t)(m0+r)*DIMD + col] = __float2bfloat16(v);
      }
    }
  }
}

// ---------------- bf16 MFMA GEMM: C = epi(A @ W^T + bias [+ res]) ----------------
template<int GELU_,int STBF,int RES>
__global__ __launch_bounds__(256) void mgemm_k(
    const bf16* __restrict__ A, const bf16* __restrict__ Bw,
    const float* __restrict__ bias, const bf16* __restrict__ res,
    void* __restrict__ Cv, int M, int K, int Nreal, int ldc)
{
  __shared__ __align__(16) short As[128*64];
  __shared__ __align__(16) short Bs[128*64];
  const int tid  = threadIdx.x;
  const int wid  = tid>>6, lane = tid&63;
  const int wr   = wid>>1, wc = wid&1;
  const int m0   = blockIdx.y*128, n0 = blockIdx.x*128;
  f32x4 acc[4][4] = {};

  const int sr = (lane>>3);
  const int sc = (lane&7)*8;

  for(int k0=0; k0<K; k0+=64){
    #pragma unroll
    for(int u=0;u<4;u++){
      const int t = wid*4 + u;
      const int r = t*8 + sr;
      const bf16* srcA = A  + (size_t)(m0+r)*K + k0 + sc;
      const bf16* srcB = Bw + (size_t)(n0+r)*K + k0 + sc;
      __builtin_amdgcn_global_load_lds((const __attribute__((address_space(1))) void*)srcA,
          (__attribute__((address_space(3))) void*)(As + t*512), 16, 0, 0);
      __builtin_amdgcn_global_load_lds((const __attribute__((address_space(1))) void*)srcB,
          (__attribute__((address_space(3))) void*)(Bs + t*512), 16, 0, 0);
    }
    asm volatile("s_waitcnt vmcnt(0)" ::: "memory");
    __syncthreads();
    #pragma unroll
    for(int ks=0;ks<2;ks++){
      bf16x8 af[4], bfr[4];
      #pragma unroll
      for(int i=0;i<4;i++){
        const int ar = wr*64 + i*16 + (lane&15);
        af[i]  = *(const bf16x8*)(As + ar*64 + ks*32 + (lane>>4)*8);
        const int br = wc*64 + i*16 + (lane&15);
        bfr[i] = *(const bf16x8*)(Bs + br*64 + ks*32 + (lane>>4)*8);
      }
      #pragma unroll
      for(int i=0;i<4;i++)
        #pragma unroll
        for(int j=0;j<4;j++)
          acc[i][j] = __builtin_amdgcn_mfma_f32_16x16x32_bf16(af[i], bfr[j], acc[i][j], 0,0,0);
    }
    __syncthreads();
  }
  #pragma unroll
  for(int i=0;i<4;i++){
    const int rbase = m0 + wr*64 + i*16 + (lane>>4)*4;
    #pragma unroll
    for(int j=0;j<4;j++){
      const int col = n0 + wc*64 + j*16 + (lane&15);
      if(col >= Nreal) continue;
      const float bv = bias[col];
      #pragma unroll
      for(int rr=0;rr<4;rr++){
        const int rowg = rbase + rr;
        float v = acc[i][j][rr] + bv;
        if constexpr(RES) v += __bfloat162float(res[(size_t)rowg*ldc + col]);
        if constexpr(GELU_){ float u=v; v = 0.5f*u*(1.f+tanhf(0.7978845608028654f*(u+0.044715f*u*u*u))); }
        if constexpr(STBF) ((bf16*)Cv)[(size_t)rowg*ldc + col] = __float2bfloat16(v);
        else               ((float*)Cv)[(size_t)rowg*ldc + col] = v;
      }
    }
  }
}

// ---------------- MSDA point prep: one THREAD per (bq, head) ----------------
__global__ __launch_bounds__(256) void msda_prep_k(
    const float* __restrict__ offaw, const float* __restrict__ refp,
    const int* __restrict__ sshapes, const int* __restrict__ lstart,
    uint2* __restrict__ pairs)
{
  const int t = blockIdx.x*256 + threadIdx.x;
  if(t >= MQ*HEADS) return;
  const int bq = t/6, h = t - bq*6;
  const int b  = bq >> 12;
  const float* row = offaw + (size_t)bq*216;
  float awv[12];
  float mx = -1e30f;
  #pragma unroll
  for(int i=0;i<12;i++){ awv[i] = row[144 + h*12 + i]; mx = fmaxf(mx, awv[i]); }
  float ssum = 0.f;
  #pragma unroll
  for(int i=0;i<12;i++){ awv[i] = __expf(awv[i]-mx); ssum += awv[i]; }
  const float inv = 1.f/ssum;
  uint2* pw = pairs + (size_t)t*48;
  int c48 = 0;
  #pragma unroll
  for(int l=0;l<LEVELS;l++){
    const int hh = sshapes[2*l], ww = sshapes[2*l+1];
    const int st = lstart[l];
    const float rx = refp[((size_t)bq*LEVELS + l)*2 + 0];
    const float ry = refp[((size_t)bq*LEVELS + l)*2 + 1];
    #pragma unroll
    for(int p=0;p<POINTS;p++){
      const float ox = row[((h*LEVELS + l)*POINTS + p)*2 + 0];
      const float oy = row[((h*LEVELS + l)*POINTS + p)*2 + 1];
      const float px = (rx + ox/(float)ww)*(float)ww - 0.5f;
      const float py = (ry + oy/(float)hh)*(float)hh - 0.5f;
      const float fx0 = floorf(px), fy0 = floorf(py);
      const int x0 = (int)fx0, y0 = (int)fy0;
      const float wx1 = px - fx0, wx0 = 1.f - wx1;
      const float wy1 = py - fy0, wy0 = 1.f - wy1;
      const float aww = awv[l*POINTS+p]*inv;
      #pragma unroll
      for(int c=0;c<4;c++){
        const int xi = x0 + (c&1);
        const int yi = y0 + (c>>1);
        const float wgt = (c&1 ? wx1 : wx0) * (c>>1 ? wy1 : wy0);
        const bool valid = (xi>=0) & (xi<=ww-1) & (yi>=0) & (yi<=hh-1);
        const int cx = min(max(xi,0), ww-1);
        const int cy = min(max(yi,0), hh-1);
        const unsigned off = (unsigned)((((b*NV + st + cy*ww + cx)*DIMD) + h*DH)*2);
        const float w = valid ? wgt*aww : 0.f;
        uint2 pr; pr.x = off; pr.y = __float_as_uint(w);
        pw[c48++] = pr;
      }
    }
  }
}

// ---------------- MSDA gather: half-wave (32 lanes) per (bq,h), 2 ch/lane ----------------
__global__ __launch_bounds__(256) void msda_gather_k(
    const bf16* __restrict__ v, const uint2* __restrict__ pairs,
    bf16* __restrict__ out)
{
  const int wid  = blockIdx.x*4 + (threadIdx.x>>6);
  const int lane = threadIdx.x & 63;
  const int pid  = wid*2 + (lane>>5);
  const int ch   = lane & 31;
  const uint2* pw = pairs + (size_t)pid*48;
  const char* vb = (const char*)v;
  float a0 = 0.f, a1 = 0.f;
  #pragma unroll
  for(int c=0;c<48;c++){
    const uint2 pr = pw[c];
    const unsigned g = *(const unsigned*)(vb + pr.x + (ch<<2));
    const float w = __uint_as_float(pr.y);
    const float lo = __uint_as_float(g << 16);
    const float hi = __uint_as_float(g & 0xffff0000u);
    a0 = fmaf(w, lo, a0);
    a1 = fmaf(w, hi, a1);
  }
  const int bq = pid/6, h = pid - bq*6;
  const unsigned u0 = (unsigned)__builtin_bit_cast(unsigned short, __float2bfloat16(a0));
  const unsigned u1 = (unsigned)__builtin_bit_cast(unsigned short, __float2bfloat16(a1));
  *(unsigned*)((char*)out + (size_t)bq*768 + h*128 + (ch<<2)) = u0 | (u1<<16);
}

// ---------------- launcher ----------------
static inline size_t rnd(size_t x){ return (x + 511) & ~(size_t)511; }

extern "C" void kernel_launch(void* const* d_in, const int* in_sizes, int n_in,
                              void* d_out, int out_size, void* d_ws, size_t ws_size,
                              hipStream_t stream)
{
  const float* query = (const float*)d_in[0];
  const float* refp  = (const float*)d_in[1];
  const float* feat  = (const float*)d_in[2];
  const int*   sshp  = (const int*)d_in[3];
  const int*   lst   = (const int*)d_in[4];
  const float* qn_g  = (const float*)d_in[5];
  const float* qn_b  = (const float*)d_in[6];
  const float* fn_g  = (const float*)d_in[7];
  const float* fn_b  = (const float*)d_in[8];
  const float* W_off = (const float*)d_in[9];
  const float* b_off = (const float*)d_in[10];
  const float* W_aw  = (const float*)d_in[11];
  const float* b_aw  = (const float*)d_in[12];
  const float* W_v   = (const float*)d_in[13];
  const float* b_v   = (const float*)d_in[14];
  const float* W_o   = (const float*)d_in[15];
  const float* b_o   = (const float*)d_in[16];
  const float* n1_g  = (const float*)d_in[17];
  const float* n1_b  = (const float*)d_in[18];
  const float* W1    = (const float*)d_in[19];
  const float* b1    = (const float*)d_in[20];
  const float* W2    = (const float*)d_in[21];
  const float* b2    = (const float*)d_in[22];
  const float* n2_g  = (const float*)d_in[23];
  const float* n2_b  = (const float*)d_in[24];
  const float* gam   = (const float*)d_in[25];

  // ---- workspace layout (~160 MB) ----
  char* p = (char*)d_ws;
  bf16* vbuf  = (bf16*)p;  p += rnd((size_t)MV*DIMD*2);
  bf16* qn    = (bf16*)p;  p += rnd((size_t)MQ*DIMD*2);
  bf16* wvg   = (bf16*)p;  p += rnd((size_t)147456*2);
  bf16* wo    = (bf16*)p;  p += rnd((size_t)147456*2);
  bf16* w1    = (bf16*)p;  p += rnd((size_t)393216*2);
  bf16* w2    = (bf16*)p;  p += rnd((size_t)393216*2);
  bf16* wcat  = (bf16*)p;  p += rnd((size_t)98304*2);
  float* bcat = (float*)p; p += rnd((size_t)256*4);
  float* u1   = (float*)p; p += rnd((size_t)384*4);
  float* c0   = (float*)p; p += rnd((size_t)384*4);
  bf16* hbuf  = (bf16*)p;  p += rnd((size_t)MQ*FFN*2);
  bf16* ybuf  = (bf16*)p;  p += rnd((size_t)MQ*DIMD*2);
  float* offaw = (float*)p; p += rnd((size_t)MQ*216*4);
  bf16*  msda  = (bf16*)p;  p += rnd((size_t)MQ*DIMD*2);
  bf16*  x1    = (bf16*)p;  p += rnd((size_t)MQ*DIMD*2);
  bf16*  x2    = (bf16*)p;  p += rnd((size_t)MQ*DIMD*2);
  // pairs table (37.7 MB) aliases hbuf+ybuf (both dead until FFN steps)
  uint2* pairs = (uint2*)hbuf;

  // 1. weights -> bf16 (+g-fold, concat/pad) ; v-proj LN constants
  prep_k<<<4609, 256, 0, stream>>>(W_v, W_o, W1, W2, W_off, W_aw, b_off, b_aw,
                                   fn_g, wvg, wo, w1, w2, wcat, bcat);
  vprep_k<<<DIMD/4, 256, 0, stream>>>(W_v, fn_g, fn_b, b_v, u1, c0);
  // 2. qn = LN(query) bf16
  ln_k<0,1,0><<<MQ/4, 256, 0, stream>>>(query, qn_g, qn_b, nullptr, nullptr, qn, MQ);
  // 3. v = LN(feat) @ W_v^T + b_v  (fused v3: 64-row blocks, spill-free)
  vproj3_k<<<MV/64, 512, 0, stream>>>(feat, wvg, u1, c0, vbuf);
  // 4. offsets|logits = qn @ Wcat^T + bcat  (fp32, ldc 216, Npad 256)
  mgemm_k<0,0,0><<<dim3(2, MQ/128), 256, 0, stream>>>(qn, wcat, bcat, nullptr, offaw,
                                                      MQ, DIMD, 216, 216);
  // 4.5 point prep
  msda_prep_k<<<(MQ*HEADS + 255)/256, 256, 0, stream>>>(offaw, refp, sshp, lst, pairs);
  // 5. gather -> msda bf16
  msda_gather_k<<<MQ*HEADS/8, 256, 0, stream>>>(vbuf, pairs, msda);
  // 6. x1 = qn + msda @ W_o^T + b_o  (bf16)
  mgemm_k<0,1,1><<<dim3(3, MQ/128), 256, 0, stream>>>(msda, wo, b_o, qn, x1,
                                                      MQ, DIMD, DIMD, DIMD);
  // 7. x2 = LN(x1) bf16
  ln_k<1,1,0><<<MQ/4, 256, 0, stream>>>(x1, n1_g, n1_b, nullptr, nullptr, x2, MQ);
  // 8. h = gelu(x2 @ W1^T + b1)  (bf16)
  mgemm_k<1,1,0><<<dim3(8, MQ/128), 256, 0, stream>>>(x2, w1, b1, nullptr, hbuf,
                                                      MQ, DIMD, FFN, FFN);
  // 9. y = x2 + h @ W2^T + b2  (bf16)
  mgemm_k<0,1,1><<<dim3(3, MQ/128), 256, 0, stream>>>(hbuf, w2, b2, x2, ybuf,
                                                      MQ, FFN, DIMD, DIMD);
  // 10. out = query + gamma * LN(y)
  ln_k<1,0,1><<<MQ/4, 256, 0, stream>>>(ybuf, n2_g, n2_b, query, gam, (float*)d_out, MQ);
}

// Round 7
// 266.170 us; speedup vs baseline: 1.6374x; 1.1632x over previous
//
#include <hip/hip_runtime.h>
#include <hip/hip_bf16.h>

// ---------------- problem constants ----------------
#define DIMD 384
#define HEADS 6
#define DH 64
#define LEVELS 3
#define POINTS 4
#define FFN 1024
#define BB 4
#define NQ 4096
#define NV 21504
#define MQ (BB*NQ)   // 16384
#define MV (BB*NV)   // 86016
#define EPSF 1e-6f

typedef __hip_bfloat16 bf16;
typedef __attribute__((ext_vector_type(8))) short bf16x8;
typedef __attribute__((ext_vector_type(4))) float f32x4;

__device__ __forceinline__ float wave_sum(float v){
  #pragma unroll
  for(int o=32;o;o>>=1) v += __shfl_xor(v,o);
  return v;
}

// ---------------- weight prep: fp32 -> bf16 (+ concat/pad W_off|W_aw) ----------------
__global__ __launch_bounds__(256) void prep_k(
  const float* __restrict__ Wv, const float* __restrict__ Wo,
  const float* __restrict__ W1, const float* __restrict__ W2,
  const float* __restrict__ Woff, const float* __restrict__ Waw,
  const float* __restrict__ boff, const float* __restrict__ baw,
  bf16* __restrict__ wv, bf16* __restrict__ wo, bf16* __restrict__ w1,
  bf16* __restrict__ w2, bf16* __restrict__ wcat, float* __restrict__ bcat)
{
  int i = blockIdx.x*256 + threadIdx.x;
  if(i < 147456){ wv[i] = __float2bfloat16(Wv[i]); return; }
  i -= 147456;
  if(i < 147456){ wo[i] = __float2bfloat16(Wo[i]); return; }
  i -= 147456;
  if(i < 393216){ w1[i] = __float2bfloat16(W1[i]); return; }
  i -= 393216;
  if(i < 393216){ w2[i] = __float2bfloat16(W2[i]); return; }
  i -= 393216;
  if(i < 98304){
    int r = i/384, c = i - r*384;
    float v = r<144 ? Woff[r*384+c] : (r<216 ? Waw[(r-144)*384+c] : 0.f);
    wcat[i] = __float2bfloat16(v); return;
  }
  i -= 98304;
  if(i < 256){ bcat[i] = i<144 ? boff[i] : (i<216 ? baw[i-144] : 0.f); }
}

// ---------------- row LayerNorm (DIMD=384), templated in/out dtype ----------------
template<int INBF,int OUTBF,int FINAL>
__global__ __launch_bounds__(256) void ln_k(const void* __restrict__ xv,
    const float* __restrict__ g, const float* __restrict__ b,
    const float* __restrict__ q, const float* __restrict__ gamma,
    void* __restrict__ outv, int nrows)
{
  int row = blockIdx.x*4 + (threadIdx.x>>6);
  int lane = threadIdx.x & 63;
  if(row >= nrows) return;
  float vals[6];
  float s=0.f, s2=0.f;
  #pragma unroll
  for(int i=0;i<6;i++){
    float v;
    if constexpr(INBF) v = __bfloat162float(((const bf16*)xv)[(size_t)row*DIMD + lane + i*64]);
    else               v = ((const float*)xv)[(size_t)row*DIMD + lane + i*64];
    vals[i]=v; s += v; s2 += v*v;
  }
  s = wave_sum(s); s2 = wave_sum(s2);
  float m = s*(1.f/DIMD);
  float var = s2*(1.f/DIMD) - m*m;
  float r = rsqrtf(var + EPSF);
  #pragma unroll
  for(int i=0;i<6;i++){
    int k = lane + i*64;
    float t = (vals[i]-m)*r*g[k] + b[k];
    if constexpr(FINAL){
      t = q[(size_t)row*DIMD + k] + gamma[k]*t;
      ((float*)outv)[(size_t)row*DIMD + k] = t;
    } else if constexpr(OUTBF){
      ((bf16*)outv)[(size_t)row*DIMD + k] = __float2bfloat16(t);
    } else {
      ((float*)outv)[(size_t)row*DIMD + k] = t;
    }
  }
}

// ---------------- value projection: 64x384 tile, A read ONCE ----------------
// out[64][384] = A[64 rows][384] @ W^T[384][384] + bias. 512 thr = 8 waves,
// wave n-slice 48 cols, acc[4][3]. Both operands via global_load_lds (m97-style).
__global__ __launch_bounds__(512,4) void vgemm_k(
    const bf16* __restrict__ A, const bf16* __restrict__ Bw,
    const float* __restrict__ bias, bf16* __restrict__ out)
{
  __shared__ __align__(16) short As[64*64];     // 8 KB
  __shared__ __align__(16) short Bs[384*64];    // 48 KB
  const int tid = threadIdx.x;
  const int wid = tid>>6, lane = tid&63;
  const int m0 = blockIdx.x*64;
  f32x4 acc[4][3] = {};
  const int lr8 = lane>>3;            // 0..7
  const int lc8 = (lane&7)*8;         // 0..56

  for(int k0=0; k0<DIMD; k0+=64){
    // A: 8 instrs (1 per wave), rows wid*8..+7
    {
      const bf16* srcA = A + (size_t)(m0 + wid*8 + lr8)*DIMD + k0 + lc8;
      __builtin_amdgcn_global_load_lds((const __attribute__((address_space(1))) void*)srcA,
          (__attribute__((address_space(3))) void*)(As + wid*512), 16, 0, 0);
    }
    // B: 48 instrs (6 per wave), rows t*8..+7 of the full 384
    #pragma unroll
    for(int u=0;u<6;u++){
      const int t = wid*6 + u;
      const bf16* srcB = Bw + (size_t)(t*8 + lr8)*DIMD + k0 + lc8;
      __builtin_amdgcn_global_load_lds((const __attribute__((address_space(1))) void*)srcB,
          (__attribute__((address_space(3))) void*)(Bs + t*512), 16, 0, 0);
    }
    asm volatile("s_waitcnt vmcnt(0)" ::: "memory");
    __syncthreads();
    #pragma unroll
    for(int ks=0;ks<2;ks++){
      const int cbase = ks*32 + (lane>>4)*8;
      bf16x8 af[4], bfr[3];
      #pragma unroll
      for(int i=0;i<4;i++){
        const int ar = i*16 + (lane&15);
        af[i] = *(const bf16x8*)(As + ar*64 + cbase);
      }
      #pragma unroll
      for(int j=0;j<3;j++){
        const int br = wid*48 + j*16 + (lane&15);
        bfr[j] = *(const bf16x8*)(Bs + br*64 + cbase);
      }
      #pragma unroll
      for(int i=0;i<4;i++)
        #pragma unroll
        for(int j=0;j<3;j++)
          acc[i][j] = __builtin_amdgcn_mfma_f32_16x16x32_bf16(af[i], bfr[j], acc[i][j], 0,0,0);
    }
    __syncthreads();
  }
  #pragma unroll
  for(int i=0;i<4;i++){
    const int r0 = m0 + i*16 + (lane>>4)*4;
    #pragma unroll
    for(int j=0;j<3;j++){
      const int col = wid*48 + j*16 + (lane&15);
      const float bv = bias[col];
      #pragma unroll
      for(int rr=0;rr<4;rr++)
        out[(size_t)(r0+rr)*DIMD + col] = __float2bfloat16(acc[i][j][rr] + bv);
    }
  }
}

// ---------------- bf16 MFMA GEMM: C = epi(A @ W^T + bias [+ res]) ----------------
template<int GELU_,int STBF,int RES>
__global__ __launch_bounds__(256) void mgemm_k(
    const bf16* __restrict__ A, const bf16* __restrict__ Bw,
    const float* __restrict__ bias, const bf16* __restrict__ res,
    void* __restrict__ Cv, int M, int K, int Nreal, int ldc)
{
  __shared__ __align__(16) short As[128*64];
  __shared__ __align__(16) short Bs[128*64];
  const int tid  = threadIdx.x;
  const int wid  = tid>>6, lane = tid&63;
  const int wr   = wid>>1, wc = wid&1;
  const int m0   = blockIdx.y*128, n0 = blockIdx.x*128;
  f32x4 acc[4][4] = {};

  const int sr = (lane>>3);
  const int sc = (lane&7)*8;

  for(int k0=0; k0<K; k0+=64){
    #pragma unroll
    for(int u=0;u<4;u++){
      const int t = wid*4 + u;
      const int r = t*8 + sr;
      const bf16* srcA = A  + (size_t)(m0+r)*K + k0 + sc;
      const bf16* srcB = Bw + (size_t)(n0+r)*K + k0 + sc;
      __builtin_amdgcn_global_load_lds((const __attribute__((address_space(1))) void*)srcA,
          (__attribute__((address_space(3))) void*)(As + t*512), 16, 0, 0);
      __builtin_amdgcn_global_load_lds((const __attribute__((address_space(1))) void*)srcB,
          (__attribute__((address_space(3))) void*)(Bs + t*512), 16, 0, 0);
    }
    asm volatile("s_waitcnt vmcnt(0)" ::: "memory");
    __syncthreads();
    #pragma unroll
    for(int ks=0;ks<2;ks++){
      bf16x8 af[4], bfr[4];
      #pragma unroll
      for(int i=0;i<4;i++){
        const int ar = wr*64 + i*16 + (lane&15);
        af[i]  = *(const bf16x8*)(As + ar*64 + ks*32 + (lane>>4)*8);
        const int br = wc*64 + i*16 + (lane&15);
        bfr[i] = *(const bf16x8*)(Bs + br*64 + ks*32 + (lane>>4)*8);
      }
      #pragma unroll
      for(int i=0;i<4;i++)
        #pragma unroll
        for(int j=0;j<4;j++)
          acc[i][j] = __builtin_amdgcn_mfma_f32_16x16x32_bf16(af[i], bfr[j], acc[i][j], 0,0,0);
    }
    __syncthreads();
  }
  #pragma unroll
  for(int i=0;i<4;i++){
    const int rbase = m0 + wr*64 + i*16 + (lane>>4)*4;
    #pragma unroll
    for(int j=0;j<4;j++){
      const int col = n0 + wc*64 + j*16 + (lane&15);
      if(col >= Nreal) continue;
      const float bv = bias[col];
      #pragma unroll
      for(int rr=0;rr<4;rr++){
        const int rowg = rbase + rr;
        float v = acc[i][j][rr] + bv;
        if constexpr(RES) v += __bfloat162float(res[(size_t)rowg*ldc + col]);
        if constexpr(GELU_){ float u=v; v = 0.5f*u*(1.f+tanhf(0.7978845608028654f*(u+0.044715f*u*u*u))); }
        if constexpr(STBF) ((bf16*)Cv)[(size_t)rowg*ldc + col] = __float2bfloat16(v);
        else               ((float*)Cv)[(size_t)rowg*ldc + col] = v;
      }
    }
  }
}

// ---------------- MSDA fused prep + gather ----------------
// block = 256 thr handles 8 (bq,h) pids. Phase 1: threads 0..95 (pid x point)
// compute softmax-folded bilinear corner pairs into LDS. Phase 2: half-wave
// per pid, 2 ch/lane, 48 fma-gathers.
__global__ __launch_bounds__(256) void msda_k(
    const bf16* __restrict__ v, const float* __restrict__ offaw,
    const float* __restrict__ refp, const int* __restrict__ sshapes,
    const int* __restrict__ lstart, bf16* __restrict__ out)
{
  __shared__ uint2 plds[8][48];
  const int pid0 = blockIdx.x*8;
  const int tid = threadIdx.x;
  if(tid < 96){
    const int pl = tid/12, p12 = tid - pl*12;
    const int pid = pid0 + pl;
    const int bq = pid/6, h = pid - bq*6;
    const int b  = bq >> 12;
    const float* row = offaw + (size_t)bq*216;
    // softmax over this head's 12 logits (redundant per point-thread, cached)
    float mx = -1e30f;
    #pragma unroll
    for(int i=0;i<12;i++) mx = fmaxf(mx, row[144 + h*12 + i]);
    float ssum = 0.f, my = 0.f;
    #pragma unroll
    for(int i=0;i<12;i++){
      const float e = __expf(row[144 + h*12 + i] - mx);
      ssum += e;
      if(i==p12) my = e;
    }
    const float aww = my/ssum;
    const int l = p12>>2, pp = p12&3;
    const int hh = sshapes[2*l], ww = sshapes[2*l+1];
    const int st = lstart[l];
    const float rx = refp[((size_t)bq*LEVELS + l)*2 + 0];
    const float ry = refp[((size_t)bq*LEVELS + l)*2 + 1];
    const float ox = row[(h*12 + p12)*2 + 0];
    const float oy = row[(h*12 + p12)*2 + 1];
    const float px = (rx + ox/(float)ww)*(float)ww - 0.5f;
    const float py = (ry + oy/(float)hh)*(float)hh - 0.5f;
    const float fx0 = floorf(px), fy0 = floorf(py);
    const int x0 = (int)fx0, y0 = (int)fy0;
    const float wx1 = px - fx0, wx0 = 1.f - wx1;
    const float wy1 = py - fy0, wy0 = 1.f - wy1;
    #pragma unroll
    for(int c=0;c<4;c++){
      const int xi = x0 + (c&1);
      const int yi = y0 + (c>>1);
      const float wgt = (c&1 ? wx1 : wx0) * (c>>1 ? wy1 : wy0);
      const bool valid = (xi>=0) & (xi<=ww-1) & (yi>=0) & (yi<=hh-1);
      const int cx = min(max(xi,0), ww-1);
      const int cy = min(max(yi,0), hh-1);
      const unsigned off = (unsigned)((((b*NV + st + cy*ww + cx)*DIMD) + h*DH)*2);
      uint2 pr; pr.x = off; pr.y = __float_as_uint(valid ? wgt*aww : 0.f);
      plds[pl][p12*4 + c] = pr;
    }
  }
  __syncthreads();
  const int pl  = (tid>>5);          // 0..7 half-wave id
  const int pid = pid0 + pl;
  const int ch  = tid & 31;
  const char* vb = (const char*)v;
  float a0 = 0.f, a1 = 0.f;
  #pragma unroll
  for(int c=0;c<48;c++){
    const uint2 pr = plds[pl][c];
    const unsigned g = *(const unsigned*)(vb + pr.x + (ch<<2));
    const float w = __uint_as_float(pr.y);
    a0 = fmaf(w, __uint_as_float(g << 16), a0);
    a1 = fmaf(w, __uint_as_float(g & 0xffff0000u), a1);
  }
  const int bq = pid/6, h = pid - bq*6;
  const unsigned u0 = (unsigned)__builtin_bit_cast(unsigned short, __float2bfloat16(a0));
  const unsigned u1 = (unsigned)__builtin_bit_cast(unsigned short, __float2bfloat16(a1));
  *(unsigned*)((char*)out + (size_t)bq*768 + h*128 + (ch<<2)) = u0 | (u1<<16);
}

// ---------------- launcher ----------------
static inline size_t rnd(size_t x){ return (x + 511) & ~(size_t)511; }

extern "C" void kernel_launch(void* const* d_in, const int* in_sizes, int n_in,
                              void* d_out, int out_size, void* d_ws, size_t ws_size,
                              hipStream_t stream)
{
  const float* query = (const float*)d_in[0];
  const float* refp  = (const float*)d_in[1];
  const float* feat  = (const float*)d_in[2];
  const int*   sshp  = (const int*)d_in[3];
  const int*   lst   = (const int*)d_in[4];
  const float* qn_g  = (const float*)d_in[5];
  const float* qn_b  = (const float*)d_in[6];
  const float* fn_g  = (const float*)d_in[7];
  const float* fn_b  = (const float*)d_in[8];
  const float* W_off = (const float*)d_in[9];
  const float* b_off = (const float*)d_in[10];
  const float* W_aw  = (const float*)d_in[11];
  const float* b_aw  = (const float*)d_in[12];
  const float* W_v   = (const float*)d_in[13];
  const float* b_v   = (const float*)d_in[14];
  const float* W_o   = (const float*)d_in[15];
  const float* b_o   = (const float*)d_in[16];
  const float* n1_g  = (const float*)d_in[17];
  const float* n1_b  = (const float*)d_in[18];
  const float* W1    = (const float*)d_in[19];
  const float* b1    = (const float*)d_in[20];
  const float* W2    = (const float*)d_in[21];
  const float* b2    = (const float*)d_in[22];
  const float* n2_g  = (const float*)d_in[23];
  const float* n2_b  = (const float*)d_in[24];
  const float* gam   = (const float*)d_in[25];

  // ---- workspace layout (aliased; ~193 MB) ----
  char* p = (char*)d_ws;
  bf16* featn = (bf16*)p;                      // [MV][384] bf16, dead after vgemm
  char* late  = p;                             // aliased region, used after step 4
  p += rnd((size_t)MV*DIMD*2);
  bf16* vbuf  = (bf16*)p;  p += rnd((size_t)MV*DIMD*2);
  bf16* qn    = (bf16*)p;  p += rnd((size_t)MQ*DIMD*2);
  bf16* wv    = (bf16*)p;  p += rnd((size_t)147456*2);
  bf16* wo    = (bf16*)p;  p += rnd((size_t)147456*2);
  bf16* w1    = (bf16*)p;  p += rnd((size_t)393216*2);
  bf16* w2    = (bf16*)p;  p += rnd((size_t)393216*2);
  bf16* wcat  = (bf16*)p;  p += rnd((size_t)98304*2);
  float* bcat = (float*)p; p += rnd((size_t)256*4);
  bf16* hbuf  = (bf16*)p;  p += rnd((size_t)MQ*FFN*2);
  bf16* ybuf  = (bf16*)p;  p += rnd((size_t)MQ*DIMD*2);
  // late-region carve (used only after featn is dead)
  char* q2 = late;
  float* offaw = (float*)q2; q2 += rnd((size_t)MQ*216*4);
  bf16*  msda  = (bf16*)q2;  q2 += rnd((size_t)MQ*DIMD*2);
  bf16*  x1    = (bf16*)q2;  q2 += rnd((size_t)MQ*DIMD*2);
  bf16*  x2    = (bf16*)q2;  q2 += rnd((size_t)MQ*DIMD*2);

  // 1. weights -> bf16 (+concat/pad)
  prep_k<<<4609, 256, 0, stream>>>(W_v, W_o, W1, W2, W_off, W_aw, b_off, b_aw,
                                   wv, wo, w1, w2, wcat, bcat);
  // 2. featn = LN(feat) bf16 ; qn = LN(query) bf16
  ln_k<0,1,0><<<MV/4, 256, 0, stream>>>(feat, fn_g, fn_b, nullptr, nullptr, featn, MV);
  ln_k<0,1,0><<<MQ/4, 256, 0, stream>>>(query, qn_g, qn_b, nullptr, nullptr, qn, MQ);
  // 3. v = featn @ W_v^T + b_v   (64x384 tile, A read once)
  vgemm_k<<<MV/64, 512, 0, stream>>>(featn, wv, b_v, vbuf);
  // 4. offsets|logits = qn @ Wcat^T + bcat  (fp32, ldc 216, Npad 256)
  mgemm_k<0,0,0><<<dim3(2, MQ/128), 256, 0, stream>>>(qn, wcat, bcat, nullptr, offaw,
                                                      MQ, DIMD, 216, 216);
  // 5. fused prep+gather -> msda bf16
  msda_k<<<MQ*HEADS/8, 256, 0, stream>>>(vbuf, offaw, refp, sshp, lst, msda);
  // 6. x1 = qn + msda @ W_o^T + b_o  (bf16)
  mgemm_k<0,1,1><<<dim3(3, MQ/128), 256, 0, stream>>>(msda, wo, b_o, qn, x1,
                                                      MQ, DIMD, DIMD, DIMD);
  // 7. x2 = LN(x1) bf16
  ln_k<1,1,0><<<MQ/4, 256, 0, stream>>>(x1, n1_g, n1_b, nullptr, nullptr, x2, MQ);
  // 8. h = gelu(x2 @ W1^T + b1)  (bf16)
  mgemm_k<1,1,0><<<dim3(8, MQ/128), 256, 0, stream>>>(x2, w1, b1, nullptr, hbuf,
                                                      MQ, DIMD, FFN, FFN);
  // 9. y = x2 + h @ W2^T + b2  (bf16)
  mgemm_k<0,1,1><<<dim3(3, MQ/128), 256, 0, stream>>>(hbuf, w2, b2, x2, ybuf,
                                                      MQ, FFN, DIMD, DIMD);
  // 10. out = query + gamma * LN(y)
  ln_k<1,0,1><<<MQ/4, 256, 0, stream>>>(ybuf, n2_g, n2_b, query, gam, (float*)d_out, MQ);
}